// Round 2
// baseline (750.917 us; speedup 1.0000x reference)
//
#include <hip/hip_runtime.h>

#define NN   100000
#define NE   1200000
#define MT   (NE + NN)      // edges + self loops
#define HH   4
#define HD   64             // H * OUT
#define NEG_SLOPE 0.2f
#define NB1  98             // ceil(NN/1024) scan blocks

// ---------------------------------------------------------------------------
// K1: content = x[:, :112] @ W  (tiled: 128 nodes x 64 outs / block,
//     4 nodes x 8 outs / thread), plus per-node scores si/sj.
// ---------------------------------------------------------------------------
__global__ __launch_bounds__(256) void k_content(
    const float* __restrict__ x, const float* __restrict__ W,
    const float* __restrict__ att, const float* __restrict__ pos_att,
    float* __restrict__ content, float* __restrict__ si, float* __restrict__ sj)
{
    __shared__ float Wl[112 * 64];     // 28672 B
    __shared__ float xsT[64 * 128];    // 32768 B, k-major, XOR-swizzled cols
    const int t = threadIdx.x;
    for (int i = t; i < 112 * 64; i += 256) Wl[i] = W[i];

    const int n0  = blockIdx.x * 128;
    const int oc  = (t & 7) * 8;       // output base (8 outs), within one head
    const int h   = oc >> 4;
    const int ng4 = (t >> 3) * 4;      // node base within block (0..124)

    float acc[4][8];
    #pragma unroll
    for (int j = 0; j < 4; ++j)
        #pragma unroll
        for (int o = 0; o < 8; ++o) acc[j][o] = 0.f;

    for (int ph = 0; ph < 2; ++ph) {
        __syncthreads();
        // stage 64 k-rows (k-major, swizzled columns)
        for (int idx = t; idx < 128 * 64; idx += 256) {
            const int nl = idx >> 6;          // node local 0..127
            const int kk = idx & 63;          // k row 0..63
            const int gn = n0 + nl;
            const float v = (gn < NN) ? x[gn * 128 + ph * 64 + kk] : 0.f;
            xsT[kk * 128 + (nl ^ ((kk & 31) << 2))] = v;
        }
        __syncthreads();
        const int klim = (ph == 0) ? 64 : 48;  // ph1 rows 48..63 are pos dims
        #pragma unroll 4
        for (int kk = 0; kk < klim; ++kk) {
            const int sw = (kk & 31) << 2;
            const float4 xv = *(const float4*)&xsT[kk * 128 + (ng4 ^ sw)];
            const int kg = ph * 64 + kk;
            const float4 w0 = *(const float4*)&Wl[kg * 64 + oc];
            const float4 w1 = *(const float4*)&Wl[kg * 64 + oc + 4];
            const float xa[4] = { xv.x, xv.y, xv.z, xv.w };
            #pragma unroll
            for (int j = 0; j < 4; ++j) {
                acc[j][0] = fmaf(xa[j], w0.x, acc[j][0]);
                acc[j][1] = fmaf(xa[j], w0.y, acc[j][1]);
                acc[j][2] = fmaf(xa[j], w0.z, acc[j][2]);
                acc[j][3] = fmaf(xa[j], w0.w, acc[j][3]);
                acc[j][4] = fmaf(xa[j], w1.x, acc[j][4]);
                acc[j][5] = fmaf(xa[j], w1.y, acc[j][5]);
                acc[j][6] = fmaf(xa[j], w1.z, acc[j][6]);
                acc[j][7] = fmaf(xa[j], w1.w, acc[j][7]);
            }
        }
    }

    // ---- scores ----
    const int dbase = oc & 15;   // 0 or 8: which half of the 16 dims/head
    float ati[8], atj[8], pti[8], ptj[8];
    #pragma unroll
    for (int j = 0; j < 8; ++j) {
        ati[j] = att[h * 32 + dbase + j];
        atj[j] = att[h * 32 + 16 + dbase + j];
        pti[j] = pos_att[h * 32 + dbase + j];
        ptj[j] = pos_att[h * 32 + 16 + dbase + j];
    }
    #pragma unroll
    for (int j = 0; j < 4; ++j) {
        const int gn = n0 + ng4 + j;
        float s1 = 0.f, s2 = 0.f;
        #pragma unroll
        for (int o = 0; o < 8; ++o) {
            s1 = fmaf(acc[j][o], ati[o], s1);
            s2 = fmaf(acc[j][o], atj[o], s2);
        }
        #pragma unroll
        for (int pp = 0; pp < 8; ++pp) {
            const int row = 48 + dbase + pp;   // pos dims live in ph1 rows 48..63
            const float pv = xsT[row * 128 + ((ng4 + j) ^ ((row & 31) << 2))];
            s1 = fmaf(pv, pti[pp], s1);
            s2 = fmaf(pv, ptj[pp], s2);
        }
        s1 += __shfl_xor(s1, 1);
        s2 += __shfl_xor(s2, 1);
        if (gn < NN) {
            if ((t & 1) == 0) si[gn * 4 + h] = s1;
            else              sj[gn * 4 + h] = s2;
        }
        // content store
        if (gn < NN) {
            float4 lo = { acc[j][0], acc[j][1], acc[j][2], acc[j][3] };
            float4 hi = { acc[j][4], acc[j][5], acc[j][6], acc[j][7] };
            *(float4*)&content[gn * 64 + oc]     = lo;
            *(float4*)&content[gn * 64 + oc + 4] = hi;
        }
    }
}

// ---------------------------------------------------------------------------
// K2: histogram of destination (col) counts
// ---------------------------------------------------------------------------
__global__ __launch_bounds__(256) void k_hist(
    const int* __restrict__ ei, int* __restrict__ cnt)
{
    const int e = blockIdx.x * 256 + threadIdx.x;
    if (e >= MT) return;
    const int c = (e < NE) ? ei[NE + e] : (e - NE);
    atomicAdd(cnt + c, 1);
}

// K3a: per-block exclusive scan of cnt (1024 elems/block), block sums out
__global__ __launch_bounds__(256) void k_scan1(
    const int* __restrict__ cnt, int* __restrict__ loc, int* __restrict__ bsum)
{
    const int b = blockIdx.x, t = threadIdx.x;
    const int base = b * 1024 + t * 4;
    int v[4], tsum = 0;
    #pragma unroll
    for (int j = 0; j < 4; ++j) {
        v[j] = (base + j < NN) ? cnt[base + j] : 0;
        tsum += v[j];
    }
    const int lane = t & 63, w = t >> 6;
    int sc = tsum;
    #pragma unroll
    for (int d = 1; d < 64; d <<= 1) {
        const int u = __shfl_up(sc, d);
        if (lane >= d) sc += u;
    }
    __shared__ int wsum[4];
    if (lane == 63) wsum[w] = sc;
    __syncthreads();
    int wbase = 0;
    for (int k = 0; k < w; ++k) wbase += wsum[k];
    int run = wbase + sc - tsum;   // exclusive prefix for this thread
    #pragma unroll
    for (int j = 0; j < 4; ++j) {
        if (base + j < NN) loc[base + j] = run;
        run += v[j];
    }
    if (t == 255) bsum[b] = wbase + sc;
}

// K3b: serial exclusive scan of the 98 block sums
__global__ void k_scan2(int* __restrict__ bsum)
{
    if (threadIdx.x == 0 && blockIdx.x == 0) {
        int run = 0;
        for (int i = 0; i < NB1; ++i) { const int v = bsum[i]; bsum[i] = run; run += v; }
    }
}

// K3c: add block bases; produce offsets and the working copy woff
__global__ __launch_bounds__(256) void k_scan3(
    int* __restrict__ offsets, const int* __restrict__ bsum, int* __restrict__ woff)
{
    const int i = blockIdx.x * 256 + threadIdx.x;
    if (i == 0) offsets[NN] = MT;
    if (i >= NN) return;
    const int off = offsets[i] + bsum[i >> 10];
    offsets[i] = off;
    woff[i] = off;
}

// ---------------------------------------------------------------------------
// K4: per edge: exp(leaky_relu(si[r]+sj[c])) ; atomic row segsum ;
//     counting-sort scatter of (r, ea4) by destination c
// ---------------------------------------------------------------------------
__global__ __launch_bounds__(256) void k_edge(
    const int* __restrict__ ei, const float* __restrict__ si,
    const float* __restrict__ sj, float* __restrict__ segsum,
    int* __restrict__ woff, int* __restrict__ sorted_r,
    float* __restrict__ sorted_ea)
{
    const int e = blockIdx.x * 256 + threadIdx.x;
    if (e >= MT) return;
    int r, c;
    if (e < NE) { r = ei[e]; c = ei[NE + e]; } else { r = e - NE; c = r; }
    const float4 s1 = *(const float4*)(si + r * 4);
    const float4 s2 = *(const float4*)(sj + c * 4);
    float a[4] = { s1.x + s2.x, s1.y + s2.y, s1.z + s2.z, s1.w + s2.w };
    float4 ea;
    float* eap = &ea.x;
    #pragma unroll
    for (int hh = 0; hh < 4; ++hh) {
        float v = a[hh];
        v = v > 0.f ? v : NEG_SLOPE * v;
        const float ev = expf(v);
        eap[hh] = ev;
        atomicAdd(segsum + r * 4 + hh, ev);
    }
    const int pos = atomicAdd(woff + c, 1);
    sorted_r[pos] = r;
    *(float4*)(sorted_ea + (size_t)pos * 4) = ea;
}

// ---------------------------------------------------------------------------
// K5: one wave per destination node: walk CSR segment, accumulate
//     content[r]*alpha in registers, one coalesced write; gram accumulation.
// ---------------------------------------------------------------------------
__global__ __launch_bounds__(256) void k_gather(
    const int* __restrict__ offsets, const int* __restrict__ sorted_r,
    const float* __restrict__ sorted_ea, const float* __restrict__ segsum,
    const float* __restrict__ content, const float* __restrict__ bias,
    float* __restrict__ out, double* __restrict__ pairs)
{
    const int lane = threadIdx.x & 63;
    const int wid  = threadIdx.x >> 6;
    const int n    = blockIdx.x * 4 + wid;   // grid sized so n < NN exactly
    const int h    = lane >> 4;
    const int s0 = offsets[n], s1 = offsets[n + 1];
    float acc = 0.f;
    float a0=0,a1=0,a2=0,a3=0,a4=0,a5=0,a6=0,a7=0,a8=0,a9=0;
    int i = s0;
    for (; i + 1 < s1; i += 2) {
        const int r0 = sorted_r[i], r1 = sorted_r[i + 1];
        const float ea0 = sorted_ea[i * 4 + h];
        const float ea1 = sorted_ea[(i + 1) * 4 + h];
        const float ss0 = segsum[r0 * 4 + h];
        const float ss1 = segsum[r1 * 4 + h];
        const float al0 = ea0 / (ss0 + 1e-10f);
        const float al1 = ea1 / (ss1 + 1e-10f);
        acc = fmaf(content[r0 * 64 + lane], al0, acc);
        acc = fmaf(content[r1 * 64 + lane], al1, acc);
        {
            const float v0 = al0;
            const float v1 = __shfl_xor(al0, 16);
            const float v2 = __shfl_xor(al0, 32);
            const float v3 = __shfl_xor(al0, 48);
            a0=fmaf(v0,v0,a0); a1=fmaf(v0,v1,a1); a2=fmaf(v0,v2,a2); a3=fmaf(v0,v3,a3);
            a4=fmaf(v1,v1,a4); a5=fmaf(v1,v2,a5); a6=fmaf(v1,v3,a6);
            a7=fmaf(v2,v2,a7); a8=fmaf(v2,v3,a8); a9=fmaf(v3,v3,a9);
        }
        {
            const float v0 = al1;
            const float v1 = __shfl_xor(al1, 16);
            const float v2 = __shfl_xor(al1, 32);
            const float v3 = __shfl_xor(al1, 48);
            a0=fmaf(v0,v0,a0); a1=fmaf(v0,v1,a1); a2=fmaf(v0,v2,a2); a3=fmaf(v0,v3,a3);
            a4=fmaf(v1,v1,a4); a5=fmaf(v1,v2,a5); a6=fmaf(v1,v3,a6);
            a7=fmaf(v2,v2,a7); a8=fmaf(v2,v3,a8); a9=fmaf(v3,v3,a9);
        }
    }
    if (i < s1) {
        const int r0 = sorted_r[i];
        const float ea0 = sorted_ea[i * 4 + h];
        const float ss0 = segsum[r0 * 4 + h];
        const float al0 = ea0 / (ss0 + 1e-10f);
        acc = fmaf(content[r0 * 64 + lane], al0, acc);
        const float v0 = al0;
        const float v1 = __shfl_xor(al0, 16);
        const float v2 = __shfl_xor(al0, 32);
        const float v3 = __shfl_xor(al0, 48);
        a0=fmaf(v0,v0,a0); a1=fmaf(v0,v1,a1); a2=fmaf(v0,v2,a2); a3=fmaf(v0,v3,a3);
        a4=fmaf(v1,v1,a4); a5=fmaf(v1,v2,a5); a6=fmaf(v1,v3,a6);
        a7=fmaf(v2,v2,a7); a8=fmaf(v2,v3,a8); a9=fmaf(v3,v3,a9);
    }
    out[n * 64 + lane] = acc + bias[lane];

    __shared__ double red[4][10];
    if (lane == 0) {    // lane 0 has the canonical head ordering
        red[wid][0]=a0; red[wid][1]=a1; red[wid][2]=a2; red[wid][3]=a3; red[wid][4]=a4;
        red[wid][5]=a5; red[wid][6]=a6; red[wid][7]=a7; red[wid][8]=a8; red[wid][9]=a9;
    }
    __syncthreads();
    if (threadIdx.x < 10) {
        const double s = red[0][threadIdx.x] + red[1][threadIdx.x]
                       + red[2][threadIdx.x] + red[3][threadIdx.x];
        atomicAdd(pairs + threadIdx.x, s);
    }
}

// K6: finalize diversity loss
__global__ void k_loss(const double* __restrict__ ps, float* __restrict__ out)
{
    if (threadIdx.x == 0 && blockIdx.x == 0) {
        const double s00=ps[0], s01=ps[1], s02=ps[2], s03=ps[3], s11=ps[4];
        const double s12=ps[5], s13=ps[6], s22=ps[7], s23=ps[8], s33=ps[9];
        const double n0 = fmax(sqrt(s00), 1e-12);
        const double n1 = fmax(sqrt(s11), 1e-12);
        const double n2 = fmax(sqrt(s22), 1e-12);
        const double n3 = fmax(sqrt(s33), 1e-12);
        double loss = 2.0 * ( s01/(n0*n1) + s02/(n0*n2) + s03/(n0*n3)
                            + s12/(n1*n2) + s13/(n1*n3) + s23/(n2*n3) );
        loss = loss / 16.0 * 0.1;
        out[NN * HD] = (float)loss;
    }
}

extern "C" void kernel_launch(void* const* d_in, const int* in_sizes, int n_in,
                              void* d_out, int out_size, void* d_ws, size_t ws_size,
                              hipStream_t stream)
{
    const float* x       = (const float*)d_in[0];
    const int*   ei      = (const int*)d_in[1];
    const float* W       = (const float*)d_in[2];
    const float* att     = (const float*)d_in[3];
    const float* pos_att = (const float*)d_in[4];
    const float* bias    = (const float*)d_in[5];
    float* out = (float*)d_out;

    // workspace layout (all 16B aligned)
    char* p = (char*)d_ws;
    double* pairs   = (double*)p;            p += 128;                      // 16 doubles
    float* segsum   = (float*)p;             p += (size_t)NN * 4 * 4;       // 1.6 MB
    int*   cnt      = (int*)p;               p += (size_t)NN * 4;           // 400 KB (reused as woff)
    int*   offsets  = (int*)p;               p += (size_t)(NN + 4) * 4;     // 400 KB
    int*   bsum     = (int*)p;               p += 512;
    int*   sorted_r = (int*)p;               p += (size_t)MT * 4;           // 5.2 MB
    float* si       = (float*)p;             p += (size_t)NN * 4 * 4;
    float* sj       = (float*)p;             p += (size_t)NN * 4 * 4;
    float* content  = (float*)p;             p += (size_t)NN * 64 * 4;      // 25.6 MB
    float* sorted_ea= (float*)p;             p += (size_t)MT * 4 * 4;       // 20.8 MB

    // zero pairs + segsum + cnt (contiguous region)
    hipMemsetAsync(pairs, 0, 128 + (size_t)NN * 16 + (size_t)NN * 4, stream);

    k_content<<<(NN + 127) / 128, 256, 0, stream>>>(x, W, att, pos_att, content, si, sj);
    k_hist   <<<(MT + 255) / 256, 256, 0, stream>>>(ei, cnt);
    k_scan1  <<<NB1, 256, 0, stream>>>(cnt, offsets, bsum);
    k_scan2  <<<1, 64, 0, stream>>>(bsum);
    k_scan3  <<<(NN + 255) / 256, 256, 0, stream>>>(offsets, bsum, cnt);   // cnt becomes woff
    k_edge   <<<(MT + 255) / 256, 256, 0, stream>>>(ei, si, sj, segsum, cnt, sorted_r, sorted_ea);
    k_gather <<<NN / 4, 256, 0, stream>>>(offsets, sorted_r, sorted_ea, segsum,
                                          content, bias, out, pairs);
    k_loss   <<<1, 64, 0, stream>>>(pairs, out);
}

// Round 3
// 564.161 us; speedup vs baseline: 1.3310x; 1.3310x over previous
//
#include <hip/hip_runtime.h>

#define NN   100000
#define NE   1200000
#define MT   (NE + NN)      // edges + self loops
#define HH   4
#define HD   64             // H * OUT
#define NEG_SLOPE 0.2f
#define NB1  98             // ceil(NN/1024) scan blocks

// ---------------------------------------------------------------------------
// K1: content = x[:, :112] @ W  (tiled: 128 nodes x 64 outs / block,
//     4 nodes x 8 outs / thread), plus per-node scores si/sj.
// ---------------------------------------------------------------------------
__global__ __launch_bounds__(256) void k_content(
    const float* __restrict__ x, const float* __restrict__ W,
    const float* __restrict__ att, const float* __restrict__ pos_att,
    float* __restrict__ content, float* __restrict__ si, float* __restrict__ sj)
{
    __shared__ float Wl[112 * 64];     // 28672 B
    __shared__ float xsT[64 * 128];    // 32768 B, k-major, XOR-swizzled cols
    const int t = threadIdx.x;
    for (int i = t; i < 112 * 64; i += 256) Wl[i] = W[i];

    const int n0  = blockIdx.x * 128;
    const int oc  = (t & 7) * 8;       // output base (8 outs), within one head
    const int h   = oc >> 4;
    const int ng4 = (t >> 3) * 4;      // node base within block (0..124)

    float acc[4][8];
    #pragma unroll
    for (int j = 0; j < 4; ++j)
        #pragma unroll
        for (int o = 0; o < 8; ++o) acc[j][o] = 0.f;

    for (int ph = 0; ph < 2; ++ph) {
        __syncthreads();
        // stage 64 k-rows (k-major, swizzled columns)
        for (int idx = t; idx < 128 * 64; idx += 256) {
            const int nl = idx >> 6;          // node local 0..127
            const int kk = idx & 63;          // k row 0..63
            const int gn = n0 + nl;
            const float v = (gn < NN) ? x[gn * 128 + ph * 64 + kk] : 0.f;
            xsT[kk * 128 + (nl ^ ((kk & 31) << 2))] = v;
        }
        __syncthreads();
        const int klim = (ph == 0) ? 64 : 48;  // ph1 rows 48..63 are pos dims
        #pragma unroll 4
        for (int kk = 0; kk < klim; ++kk) {
            const int sw = (kk & 31) << 2;
            const float4 xv = *(const float4*)&xsT[kk * 128 + (ng4 ^ sw)];
            const int kg = ph * 64 + kk;
            const float4 w0 = *(const float4*)&Wl[kg * 64 + oc];
            const float4 w1 = *(const float4*)&Wl[kg * 64 + oc + 4];
            const float xa[4] = { xv.x, xv.y, xv.z, xv.w };
            #pragma unroll
            for (int j = 0; j < 4; ++j) {
                acc[j][0] = fmaf(xa[j], w0.x, acc[j][0]);
                acc[j][1] = fmaf(xa[j], w0.y, acc[j][1]);
                acc[j][2] = fmaf(xa[j], w0.z, acc[j][2]);
                acc[j][3] = fmaf(xa[j], w0.w, acc[j][3]);
                acc[j][4] = fmaf(xa[j], w1.x, acc[j][4]);
                acc[j][5] = fmaf(xa[j], w1.y, acc[j][5]);
                acc[j][6] = fmaf(xa[j], w1.z, acc[j][6]);
                acc[j][7] = fmaf(xa[j], w1.w, acc[j][7]);
            }
        }
    }

    // ---- scores ----
    const int dbase = oc & 15;   // 0 or 8: which half of the 16 dims/head
    float ati[8], atj[8], pti[8], ptj[8];
    #pragma unroll
    for (int j = 0; j < 8; ++j) {
        ati[j] = att[h * 32 + dbase + j];
        atj[j] = att[h * 32 + 16 + dbase + j];
        pti[j] = pos_att[h * 32 + dbase + j];
        ptj[j] = pos_att[h * 32 + 16 + dbase + j];
    }
    #pragma unroll
    for (int j = 0; j < 4; ++j) {
        const int gn = n0 + ng4 + j;
        float s1 = 0.f, s2 = 0.f;
        #pragma unroll
        for (int o = 0; o < 8; ++o) {
            s1 = fmaf(acc[j][o], ati[o], s1);
            s2 = fmaf(acc[j][o], atj[o], s2);
        }
        #pragma unroll
        for (int pp = 0; pp < 8; ++pp) {
            const int row = 48 + dbase + pp;   // pos dims live in ph1 rows 48..63
            const float pv = xsT[row * 128 + ((ng4 + j) ^ ((row & 31) << 2))];
            s1 = fmaf(pv, pti[pp], s1);
            s2 = fmaf(pv, ptj[pp], s2);
        }
        s1 += __shfl_xor(s1, 1);
        s2 += __shfl_xor(s2, 1);
        if (gn < NN) {
            if ((t & 1) == 0) si[gn * 4 + h] = s1;
            else              sj[gn * 4 + h] = s2;
        }
        if (gn < NN) {
            float4 lo = { acc[j][0], acc[j][1], acc[j][2], acc[j][3] };
            float4 hi = { acc[j][4], acc[j][5], acc[j][6], acc[j][7] };
            *(float4*)&content[gn * 64 + oc]     = lo;
            *(float4*)&content[gn * 64 + oc + 4] = hi;
        }
    }
}

// ---------------------------------------------------------------------------
// K2: histogram of destination (col) counts
// ---------------------------------------------------------------------------
__global__ __launch_bounds__(256) void k_hist(
    const int* __restrict__ ei, int* __restrict__ cnt)
{
    const int e = blockIdx.x * 256 + threadIdx.x;
    if (e >= MT) return;
    const int c = (e < NE) ? ei[NE + e] : (e - NE);
    atomicAdd(cnt + c, 1);
}

// K3a: per-block exclusive scan of cnt (1024 elems/block), block sums out
__global__ __launch_bounds__(256) void k_scan1(
    const int* __restrict__ cnt, int* __restrict__ loc, int* __restrict__ bsum)
{
    const int b = blockIdx.x, t = threadIdx.x;
    const int base = b * 1024 + t * 4;
    int v[4], tsum = 0;
    #pragma unroll
    for (int j = 0; j < 4; ++j) {
        v[j] = (base + j < NN) ? cnt[base + j] : 0;
        tsum += v[j];
    }
    const int lane = t & 63, w = t >> 6;
    int sc = tsum;
    #pragma unroll
    for (int d = 1; d < 64; d <<= 1) {
        const int u = __shfl_up(sc, d);
        if (lane >= d) sc += u;
    }
    __shared__ int wsum[4];
    if (lane == 63) wsum[w] = sc;
    __syncthreads();
    int wbase = 0;
    for (int k = 0; k < w; ++k) wbase += wsum[k];
    int run = wbase + sc - tsum;   // exclusive prefix for this thread
    #pragma unroll
    for (int j = 0; j < 4; ++j) {
        if (base + j < NN) loc[base + j] = run;
        run += v[j];
    }
    if (t == 255) bsum[b] = wbase + sc;
}

// K3b: serial exclusive scan of the 98 block sums
__global__ void k_scan2(int* __restrict__ bsum)
{
    if (threadIdx.x == 0 && blockIdx.x == 0) {
        int run = 0;
        for (int i = 0; i < NB1; ++i) { const int v = bsum[i]; bsum[i] = run; run += v; }
    }
}

// K3c: add block bases; produce offsets and the working copy woff
__global__ __launch_bounds__(256) void k_scan3(
    int* __restrict__ offsets, const int* __restrict__ bsum, int* __restrict__ woff)
{
    const int i = blockIdx.x * 256 + threadIdx.x;
    if (i == 0) offsets[NN] = MT;
    if (i >= NN) return;
    const int off = offsets[i] + bsum[i >> 10];
    offsets[i] = off;
    woff[i] = off;
}

// ---------------------------------------------------------------------------
// K4: per edge: exp(leaky_relu(si[r]+sj[c])) ; atomic row segsum ;
//     counting-sort scatter of (r, ea4) by destination c
// ---------------------------------------------------------------------------
__global__ __launch_bounds__(256) void k_edge(
    const int* __restrict__ ei, const float* __restrict__ si,
    const float* __restrict__ sj, float* __restrict__ segsum,
    int* __restrict__ woff, int* __restrict__ sorted_r,
    float* __restrict__ sorted_ea)
{
    const int e = blockIdx.x * 256 + threadIdx.x;
    if (e >= MT) return;
    int r, c;
    if (e < NE) { r = ei[e]; c = ei[NE + e]; } else { r = e - NE; c = r; }
    const float4 s1 = *(const float4*)(si + r * 4);
    const float4 s2 = *(const float4*)(sj + c * 4);
    float a[4] = { s1.x + s2.x, s1.y + s2.y, s1.z + s2.z, s1.w + s2.w };
    float4 ea;
    float* eap = &ea.x;
    #pragma unroll
    for (int hh = 0; hh < 4; ++hh) {
        float v = a[hh];
        v = v > 0.f ? v : NEG_SLOPE * v;
        const float ev = expf(v);
        eap[hh] = ev;
        atomicAdd(segsum + r * 4 + hh, ev);
    }
    const int pos = atomicAdd(woff + c, 1);
    sorted_r[pos] = r;
    *(float4*)(sorted_ea + (size_t)pos * 4) = ea;
}

// ---------------------------------------------------------------------------
// K5: coalesced alpha pass: sorted_ea -> alpha in place; gram accumulation
// ---------------------------------------------------------------------------
__global__ __launch_bounds__(256) void k_alpha(
    const int* __restrict__ sorted_r, float* __restrict__ sorted_ea,
    const float* __restrict__ segsum, double* __restrict__ pairs)
{
    const int e = blockIdx.x * 256 + threadIdx.x;
    float a0=0,a1=0,a2=0,a3=0,a4=0,a5=0,a6=0,a7=0,a8=0,a9=0;
    if (e < MT) {
        const int r = sorted_r[e];
        float4 ea = *(float4*)(sorted_ea + (size_t)e * 4);
        const float4 ss = *(const float4*)(segsum + r * 4);
        const float v0 = ea.x / (ss.x + 1e-10f);
        const float v1 = ea.y / (ss.y + 1e-10f);
        const float v2 = ea.z / (ss.z + 1e-10f);
        const float v3 = ea.w / (ss.w + 1e-10f);
        ea.x = v0; ea.y = v1; ea.z = v2; ea.w = v3;
        *(float4*)(sorted_ea + (size_t)e * 4) = ea;
        a0=v0*v0; a1=v0*v1; a2=v0*v2; a3=v0*v3; a4=v1*v1;
        a5=v1*v2; a6=v1*v3; a7=v2*v2; a8=v2*v3; a9=v3*v3;
    }
    // wave reduce
    #pragma unroll
    for (int m = 32; m >= 1; m >>= 1) {
        a0 += __shfl_xor(a0, m); a1 += __shfl_xor(a1, m);
        a2 += __shfl_xor(a2, m); a3 += __shfl_xor(a3, m);
        a4 += __shfl_xor(a4, m); a5 += __shfl_xor(a5, m);
        a6 += __shfl_xor(a6, m); a7 += __shfl_xor(a7, m);
        a8 += __shfl_xor(a8, m); a9 += __shfl_xor(a9, m);
    }
    __shared__ double red[4][10];
    const int lane = threadIdx.x & 63, wid = threadIdx.x >> 6;
    if (lane == 0) {
        red[wid][0]=a0; red[wid][1]=a1; red[wid][2]=a2; red[wid][3]=a3; red[wid][4]=a4;
        red[wid][5]=a5; red[wid][6]=a6; red[wid][7]=a7; red[wid][8]=a8; red[wid][9]=a9;
    }
    __syncthreads();
    if (threadIdx.x < 10) {
        const double s = red[0][threadIdx.x] + red[1][threadIdx.x]
                       + red[2][threadIdx.x] + red[3][threadIdx.x];
        atomicAdd(pairs + threadIdx.x, s);
    }
}

// ---------------------------------------------------------------------------
// K6: one wave per destination node. Coalesced segment-r preload + shfl
//     broadcast -> 4 independent content-row loads in flight.
// ---------------------------------------------------------------------------
__global__ __launch_bounds__(256) void k_gather(
    const int* __restrict__ offsets, const int* __restrict__ sorted_r,
    const float* __restrict__ sorted_al, const float* __restrict__ content,
    const float* __restrict__ bias, float* __restrict__ out)
{
    const int lane = threadIdx.x & 63;
    const int wid  = threadIdx.x >> 6;
    const int n    = blockIdx.x * 4 + wid;   // grid sized so n < NN exactly
    const int h    = lane >> 4;
    const int s0 = offsets[n], s1 = offsets[n + 1];
    float acc = 0.f;
    for (int base = s0; base < s1; base += 64) {
        const int cd = min(64, s1 - base);
        const int rl = (lane < cd) ? sorted_r[base + lane] : 0;
        int j = 0;
        for (; j + 3 < cd; j += 4) {
            const int r0 = __shfl(rl, j);
            const int r1 = __shfl(rl, j + 1);
            const int r2 = __shfl(rl, j + 2);
            const int r3 = __shfl(rl, j + 3);
            const float al0 = sorted_al[(size_t)(base + j) * 4 + h];
            const float al1 = sorted_al[(size_t)(base + j + 1) * 4 + h];
            const float al2 = sorted_al[(size_t)(base + j + 2) * 4 + h];
            const float al3 = sorted_al[(size_t)(base + j + 3) * 4 + h];
            const float c0 = content[(size_t)r0 * 64 + lane];
            const float c1 = content[(size_t)r1 * 64 + lane];
            const float c2 = content[(size_t)r2 * 64 + lane];
            const float c3 = content[(size_t)r3 * 64 + lane];
            acc = fmaf(c0, al0, acc);
            acc = fmaf(c1, al1, acc);
            acc = fmaf(c2, al2, acc);
            acc = fmaf(c3, al3, acc);
        }
        for (; j < cd; ++j) {
            const int r0 = __shfl(rl, j);
            const float al0 = sorted_al[(size_t)(base + j) * 4 + h];
            acc = fmaf(content[(size_t)r0 * 64 + lane], al0, acc);
        }
    }
    out[(size_t)n * 64 + lane] = acc + bias[lane];
}

// K7: finalize diversity loss
__global__ void k_loss(const double* __restrict__ ps, float* __restrict__ out)
{
    if (threadIdx.x == 0 && blockIdx.x == 0) {
        const double s00=ps[0], s01=ps[1], s02=ps[2], s03=ps[3], s11=ps[4];
        const double s12=ps[5], s13=ps[6], s22=ps[7], s23=ps[8], s33=ps[9];
        const double n0 = fmax(sqrt(s00), 1e-12);
        const double n1 = fmax(sqrt(s11), 1e-12);
        const double n2 = fmax(sqrt(s22), 1e-12);
        const double n3 = fmax(sqrt(s33), 1e-12);
        double loss = 2.0 * ( s01/(n0*n1) + s02/(n0*n2) + s03/(n0*n3)
                            + s12/(n1*n2) + s13/(n1*n3) + s23/(n2*n3) );
        loss = loss / 16.0 * 0.1;
        out[NN * HD] = (float)loss;
    }
}

extern "C" void kernel_launch(void* const* d_in, const int* in_sizes, int n_in,
                              void* d_out, int out_size, void* d_ws, size_t ws_size,
                              hipStream_t stream)
{
    const float* x       = (const float*)d_in[0];
    const int*   ei      = (const int*)d_in[1];
    const float* W       = (const float*)d_in[2];
    const float* att     = (const float*)d_in[3];
    const float* pos_att = (const float*)d_in[4];
    const float* bias    = (const float*)d_in[5];
    float* out = (float*)d_out;

    // workspace layout (all 16B aligned)
    char* p = (char*)d_ws;
    double* pairs   = (double*)p;            p += 128;                      // 16 doubles
    float* segsum   = (float*)p;             p += (size_t)NN * 4 * 4;       // 1.6 MB
    int*   cnt      = (int*)p;               p += (size_t)NN * 4;           // 400 KB (reused as woff)
    int*   offsets  = (int*)p;               p += (size_t)(NN + 4) * 4;     // 400 KB
    int*   bsum     = (int*)p;               p += 512;
    int*   sorted_r = (int*)p;               p += (size_t)MT * 4;           // 5.2 MB
    float* si       = (float*)p;             p += (size_t)NN * 4 * 4;
    float* sj       = (float*)p;             p += (size_t)NN * 4 * 4;
    float* content  = (float*)p;             p += (size_t)NN * 64 * 4;      // 25.6 MB
    float* sorted_ea= (float*)p;             p += (size_t)MT * 4 * 4;       // 20.8 MB

    // zero pairs + segsum + cnt (contiguous region)
    hipMemsetAsync(pairs, 0, 128 + (size_t)NN * 16 + (size_t)NN * 4, stream);

    k_content<<<(NN + 127) / 128, 256, 0, stream>>>(x, W, att, pos_att, content, si, sj);
    k_hist   <<<(MT + 255) / 256, 256, 0, stream>>>(ei, cnt);
    k_scan1  <<<NB1, 256, 0, stream>>>(cnt, offsets, bsum);
    k_scan2  <<<1, 64, 0, stream>>>(bsum);
    k_scan3  <<<(NN + 255) / 256, 256, 0, stream>>>(offsets, bsum, cnt);   // cnt becomes woff
    k_edge   <<<(MT + 255) / 256, 256, 0, stream>>>(ei, si, sj, segsum, cnt, sorted_r, sorted_ea);
    k_alpha  <<<(MT + 255) / 256, 256, 0, stream>>>(sorted_r, sorted_ea, segsum, pairs);
    k_gather <<<NN / 4, 256, 0, stream>>>(offsets, sorted_r, sorted_ea, content, bias, out);
    k_loss   <<<1, 64, 0, stream>>>(pairs, out);
}